// Round 4
// baseline (23747.969 us; speedup 1.0000x reference)
//
#include <hip/hip_runtime.h>
#include <stdint.h>
#include <math.h>

// Seq2seq LSTM, round-7 design.
// rnn_kernel: 64 WGs x 1024 threads. Combines every component that measured
// well across rounds 3-6 and excludes every one that measured badly:
//  - per-thread weights: flat float4 w[24] = 96 VGPRs (r3/r6's proven
//    spill-free shape; r5's w[48] hit the 128-VGPR cap and spilled).
//  - wave = one hidden unit (16 waves = 16 units = WG's 64B line). Dot rows:
//    lane&15 chunks a gate row, lane>>4 selects gate i/f/g/o. In-wave
//    16-lane reduce + replicated cell (no divergence).
//  - publish: r5's proven single-producer FULL-LINE store -- lane0 of each
//    wave drops h into gsh, one barrier, tid<16 issues ONE coalesced 16-lane
//    dword store (64B line). (Scattered lone-dword publishes -- r4/r6 --
//    doubled WRITE_SIZE and serialized consumer detection; banned.)
//  - consumers: packed-slot coalesced reads (tid<256 pull 16B each), proven
//    3-4x FETCH reduction (r4/r5/r6). Poll fan-in: 64 WGs x 64 lines = 4K
//    line-requests/round, 16x less than round-3's 65K (queueing hypothesis).
//  - x-stagers (tid 256..383) disjoint from pollers.
// Sentinel protocol byte-identical to verified rounds: 4-slot rotation,
// 0x7F7F7F7F, tid<16 clears own line in slot (t+2)&3 right after the gather
// barrier (transitive-gather proof), drained by the SAME threads' vmcnt(0)
// before they publish h_{t+2} there at step t+1; ~1300cy of dot hides the
// drain.
//
// ws: [0]      hbuf: 4 slots x 1024 dwords = 16 KB (memset 0x7F)
//     [65536]  Adec: T x 1024 bf16 decoder hidden states (1 MB)

typedef __attribute__((ext_vector_type(8))) short short8;
typedef __attribute__((ext_vector_type(4))) float f32x4;
typedef unsigned long long u64;

#define HD 1024
#define ED 512
#define TPB 256          // out_gemm / softmax block size
#define RNN_TPB 1024
#define RNN_NWG 64
#define SENT32 0x7F7F7F7Fu

#define AGT __HIP_MEMORY_SCOPE_AGENT
#define RLX __ATOMIC_RELAXED

__device__ __forceinline__ unsigned short f2bf(float f) {
  union { float f; unsigned u; } x; x.f = f;
  unsigned u = x.u;
  u += 0x7fffu + ((u >> 16) & 1u);        // RNE
  return (unsigned short)(u >> 16);
}
__device__ __forceinline__ float frcp(float x) { return __builtin_amdgcn_rcpf(x); }
__device__ __forceinline__ float fsig(float x) { return frcp(1.0f + __expf(-x)); }
__device__ __forceinline__ float ftanh(float x) { return 1.0f - 2.0f * frcp(1.0f + __expf(2.0f * x)); }

__global__ __launch_bounds__(RNN_TPB)
void rnn_kernel(const int* __restrict__ state,
                const float* __restrict__ emb,
                const float* __restrict__ encWih,
                const float* __restrict__ encWhh,
                const float* __restrict__ encbih,
                const float* __restrict__ encbhh,
                const float* __restrict__ decWhh,
                const float* __restrict__ decbih,
                const float* __restrict__ decbhh,
                unsigned int* __restrict__ hbuf,   // [4][1024] dwords (float payload)
                unsigned short* __restrict__ Adec, // [T][1024] bf16
                int S, int T) {
  __shared__ __align__(16) float vec[2][HD + ED];  // double-buffered [h|x]
  __shared__ float gsh[16];

  const int tid  = threadIdx.x;
  const int wg   = blockIdx.x;
  const int w    = tid >> 6;           // wave id == local unit 0..15
  const int lane = tid & 63;
  const int c    = lane & 15;          // 16 lanes chunk one gate row
  const int g    = lane >> 4;          // gate 0..3 (i,f,g,o)
  const int gu   = (wg << 4) + w;      // global hidden unit
  const int grow = g * HD + gu;        // global gate row

  // ---- weights in registers: 24 x float4 = 96 fp32 VGPRs (proven shape) ----
  float4 wr[24];
#pragma unroll
  for (int j = 0; j < 16; ++j)
    wr[j] = *(const float4*)&encWhh[(size_t)grow * HD + 4 * (c + 16 * j)];
#pragma unroll
  for (int j = 0; j < 8; ++j)
    wr[16 + j] = *(const float4*)&encWih[(size_t)grow * ED + 4 * (c + 16 * j)];
  float breg = encbih[grow] + encbhh[grow];

  float cs = 0.0f;                     // cell state (replicated across wave)

  for (int t = 0; t < S + T; ++t) {
    const bool dec = (t >= S);
    if (t == S) {                      // one-time decoder weight switch
#pragma unroll
      for (int j = 0; j < 16; ++j)
        wr[j] = *(const float4*)&decWhh[(size_t)grow * HD + 4 * (c + 16 * j)];
      breg = decbih[grow] + decbhh[grow];
    }

    float* vb = vec[t & 1];

    // ---- gather h_t (tid<256) and x_t (tid 256..383, encoder only) ----
    if (t == 0) {
      if (tid < 256) {
        *(float4*)&vb[4 * tid] = make_float4(0.f, 0.f, 0.f, 0.f);
      } else if (tid < 384) {
        int tok = state[0];
        *(float4*)&vb[HD + 4 * (tid - 256)] =
            *(const float4*)&emb[(size_t)tok * ED + 4 * (tid - 256)];
      }
    } else {
      if (tid < 256) {
        // packed slot: thread reads its 16B (dwords 4tid..4tid+3), coalesced
        const u64* L = (const u64*)hbuf + (((size_t)(t & 3)) << 9) + (tid << 1);
        u64 d0, d1;
        do {
          d0 = __hip_atomic_load(&L[0], RLX, AGT);
          d1 = __hip_atomic_load(&L[1], RLX, AGT);
        } while ((unsigned)d0 == SENT32 || (unsigned)(d0 >> 32) == SENT32 ||
                 (unsigned)d1 == SENT32 || (unsigned)(d1 >> 32) == SENT32);
        union { u64 u[2]; float4 f; } p;
        p.u[0] = d0; p.u[1] = d1;
        *(float4*)&vb[4 * tid] = p.f;
      } else if (tid < 384) {
        if (!dec) {
          int tok = state[t];
          *(float4*)&vb[HD + 4 * (tid - 256)] =
              *(const float4*)&emb[(size_t)tok * ED + 4 * (tid - 256)];
        }
      }
    }
    __syncthreads();

    // ---- re-sentinel own line in slot (t+2)&3: one coalesced 64B store.
    // Safe: h_t gathered => every WG finished reading slot (t+2)&3 (held
    // h_{t-2}). Drained by the SAME threads' vmcnt(0) before they publish
    // h_{t+2} into this slot at step t+1; the dot below hides the drain.
    if (tid < 16)
      __hip_atomic_store(&hbuf[(size_t)((t + 2) & 3) * HD + (wg << 4) + tid], SENT32, RLX, AGT);

    // ---- dot: gate row x vb, 4-float chunks at 16B lane stride ----
    float a0 = (c == 0) ? breg : 0.0f, a1 = 0.f, a2 = 0.f, a3 = 0.f;
    if (!dec) {
#pragma unroll
      for (int j = 0; j < 24; j += 4) {
        float4 v0 = *(const float4*)&vb[4 * (c + 16 * (j + 0))];
        float4 v1 = *(const float4*)&vb[4 * (c + 16 * (j + 1))];
        float4 v2 = *(const float4*)&vb[4 * (c + 16 * (j + 2))];
        float4 v3 = *(const float4*)&vb[4 * (c + 16 * (j + 3))];
        float4 w0 = wr[j + 0], w1 = wr[j + 1], w2 = wr[j + 2], w3 = wr[j + 3];
        a0 = fmaf(w0.x, v0.x, fmaf(w0.y, v0.y, fmaf(w0.z, v0.z, fmaf(w0.w, v0.w, a0))));
        a1 = fmaf(w1.x, v1.x, fmaf(w1.y, v1.y, fmaf(w1.z, v1.z, fmaf(w1.w, v1.w, a1))));
        a2 = fmaf(w2.x, v2.x, fmaf(w2.y, v2.y, fmaf(w2.z, v2.z, fmaf(w2.w, v2.w, a2))));
        a3 = fmaf(w3.x, v3.x, fmaf(w3.y, v3.y, fmaf(w3.z, v3.z, fmaf(w3.w, v3.w, a3))));
      }
    } else {
#pragma unroll
      for (int j = 0; j < 16; j += 4) {
        float4 v0 = *(const float4*)&vb[4 * (c + 16 * (j + 0))];
        float4 v1 = *(const float4*)&vb[4 * (c + 16 * (j + 1))];
        float4 v2 = *(const float4*)&vb[4 * (c + 16 * (j + 2))];
        float4 v3 = *(const float4*)&vb[4 * (c + 16 * (j + 3))];
        float4 w0 = wr[j + 0], w1 = wr[j + 1], w2 = wr[j + 2], w3 = wr[j + 3];
        a0 = fmaf(w0.x, v0.x, fmaf(w0.y, v0.y, fmaf(w0.z, v0.z, fmaf(w0.w, v0.w, a0))));
        a1 = fmaf(w1.x, v1.x, fmaf(w1.y, v1.y, fmaf(w1.z, v1.z, fmaf(w1.w, v1.w, a1))));
        a2 = fmaf(w2.x, v2.x, fmaf(w2.y, v2.y, fmaf(w2.z, v2.z, fmaf(w2.w, v2.w, a2))));
        a3 = fmaf(w3.x, v3.x, fmaf(w3.y, v3.y, fmaf(w3.z, v3.z, fmaf(w3.w, v3.w, a3))));
      }
    }
    float acc = (a0 + a1) + (a2 + a3);
    // reduce within each 16-lane gate-row group
    acc += __shfl_xor(acc, 1);
    acc += __shfl_xor(acc, 2);
    acc += __shfl_xor(acc, 4);
    acc += __shfl_xor(acc, 8);

    // ---- per-wave LSTM cell (replicated): gate sums at lanes 0,16,32,48 ----
    float gi = __shfl(acc, 0);
    float gf = __shfl(acc, 16);
    float gg = __shfl(acc, 32);
    float go = __shfl(acc, 48);
    float iv = fsig(gi), fv = fsig(gf), gv = ftanh(gg), ov = fsig(go);
    cs = fv * cs + iv * gv;
    float hv = ov * ftanh(cs);

    if (lane == 0) gsh[w] = hv;
    __syncthreads();                   // collect barrier (also protects vec)

    // ---- publish: tid<16, ONE coalesced 16-lane store = full 64B line ----
    if (tid < 16) {
      float h = gsh[tid];
      // drain these threads' sentinel-clear of the target slot (issued at
      // step t-1); the dot+reduce above already hid most of its latency
      asm volatile("s_waitcnt vmcnt(0)" ::: "memory");
      union { float f; unsigned u; } x; x.f = h;
      __hip_atomic_store(&hbuf[(size_t)((t + 1) & 3) * HD + (wg << 4) + tid], x.u, RLX, AGT);
      if (dec) Adec[(size_t)(t - S) * HD + (wg << 4) + tid] = f2bf(h);
    }
  }
}

// ---- output head GEMM: out[t][v] = Adec[t] . Wout[v] + bout[v] ----
// WG tile: 512 t x 64 v. Wave w: t in [w*128, w*128+128), v in [v0, v0+64).
// Per k-step (K=32): stage A-slice (512x32 bf16, padded stride) in LDS,
// 8 a-frags + 4 b-frags -> 32 MFMA per wave. Wout (206 MB) read exactly once.
#define AST 56   // Alds row stride in ushorts

__global__ __launch_bounds__(TPB)
void out_gemm(const unsigned short* __restrict__ Adec,
              const float* __restrict__ Wout,
              const float* __restrict__ bout,
              float* __restrict__ out,
              int V) {
  __shared__ __align__(16) unsigned short Alds[512 * AST]; // 56 KB
  const int tid  = threadIdx.x;
  const int wv   = tid >> 6;
  const int lane = tid & 63;
  const int col  = lane & 15;
  const int quad = lane >> 4;
  const int v0   = blockIdx.x * 64;

  f32x4 acc[4][8];
#pragma unroll
  for (int bt = 0; bt < 4; ++bt)
#pragma unroll
    for (int tt = 0; tt < 8; ++tt)
      acc[bt][tt] = (f32x4){0.f, 0.f, 0.f, 0.f};

  for (int k0 = 0; k0 < HD; k0 += 32) {
    __syncthreads();
    // stage A k-slice: 512 rows x 32 bf16 (4 x uint4 chunks per row)
#pragma unroll
    for (int i = 0; i < 8; ++i) {
      int id = tid + (i << 8);             // 0..2047
      int rt = id >> 2, c4 = id & 3;
      uint4 d = *(const uint4*)(Adec + rt * HD + k0 + (c4 << 3));
      *(uint4*)&Alds[rt * AST + (c4 << 3)] = d;
    }
    __syncthreads();
    // B fragments from global (fp32 -> bf16): lane l covers Wout[v0+bt*16+col][k0+quad*8 ..+7]
    short8 bf[4];
#pragma unroll
    for (int bt = 0; bt < 4; ++bt) {
      int v = v0 + (bt << 4) + col;
      if (v >= V) v = V - 1;
      const float4* wp = (const float4*)(Wout + (size_t)v * HD + k0 + (quad << 3));
      float4 w0 = wp[0], w1 = wp[1];
      short8 b;
      b[0] = (short)f2bf(w0.x); b[1] = (short)f2bf(w0.y);
      b[2] = (short)f2bf(w0.z); b[3] = (short)f2bf(w0.w);
      b[4] = (short)f2bf(w1.x); b[5] = (short)f2bf(w1.y);
      b[6] = (short)f2bf(w1.z); b[7] = (short)f2bf(w1.w);
      bf[bt] = b;
    }
#pragma unroll
    for (int tt = 0; tt < 8; ++tt) {
      int trow = (wv << 7) + (tt << 4) + col;
      short8 af = *(const short8*)&Alds[trow * AST + (quad << 3)];
#pragma unroll
      for (int bt = 0; bt < 4; ++bt)
        acc[bt][tt] = __builtin_amdgcn_mfma_f32_16x16x32_bf16(af, bf[bt], acc[bt][tt], 0, 0, 0);
    }
  }
  // epilogue: C/D layout col = lane&15 (v), row = quad*4 + reg (t)
#pragma unroll
  for (int bt = 0; bt < 4; ++bt) {
    int v = v0 + (bt << 4) + col;
    if (v < V) {
      float bb = bout[v];
#pragma unroll
      for (int tt = 0; tt < 8; ++tt) {
        int tb = (wv << 7) + (tt << 4) + (quad << 2);
        f32x4 a = acc[bt][tt];
        out[(size_t)(tb + 0) * V + v] = a[0] + bb;
        out[(size_t)(tb + 1) * V + v] = a[1] + bb;
        out[(size_t)(tb + 2) * V + v] = a[2] + bb;
        out[(size_t)(tb + 3) * V + v] = a[3] + bb;
      }
    }
  }
}

// ---- row softmax in place over d_out: one WG per t ----
__global__ __launch_bounds__(TPB)
void softmax_rows(float* __restrict__ out, int V) {
  float* rowp = out + (size_t)blockIdx.x * V;
  __shared__ float red[8];
  const int tid = threadIdx.x;

  float m = -1e30f;
  for (int v = tid; v < V; v += TPB) m = fmaxf(m, rowp[v]);
#pragma unroll
  for (int off = 32; off >= 1; off >>= 1) m = fmaxf(m, __shfl_xor(m, off));
  if ((tid & 63) == 0) red[tid >> 6] = m;
  __syncthreads();
  if (tid == 0) red[4] = fmaxf(fmaxf(red[0], red[1]), fmaxf(red[2], red[3]));
  __syncthreads();
  m = red[4];

  float s = 0.0f;
  for (int v = tid; v < V; v += TPB) {
    float e = expf(rowp[v] - m);
    rowp[v] = e;
    s += e;
  }
#pragma unroll
  for (int off = 32; off >= 1; off >>= 1) s += __shfl_xor(s, off);
  if ((tid & 63) == 0) red[tid >> 6] = s;
  __syncthreads();
  if (tid == 0) red[5] = red[0] + red[1] + red[2] + red[3];
  __syncthreads();
  float inv = 1.0f / red[5];
  for (int v = tid; v < V; v += TPB) rowp[v] *= inv;
}

extern "C" void kernel_launch(void* const* d_in, const int* in_sizes, int n_in,
                              void* d_out, int out_size, void* d_ws, size_t ws_size,
                              hipStream_t stream) {
  const int*   state  = (const int*)d_in[0];
  // d_in[1] = max_len scalar (T derived from out_size instead)
  const float* emb    = (const float*)d_in[2];
  const float* encWih = (const float*)d_in[3];
  const float* encWhh = (const float*)d_in[4];
  const float* encbih = (const float*)d_in[5];
  const float* encbhh = (const float*)d_in[6];
  // d_in[7] = dec_Wih (multiplied by zero input in reference -> unused)
  const float* decWhh = (const float*)d_in[8];
  const float* decbih = (const float*)d_in[9];
  const float* decbhh = (const float*)d_in[10];
  const float* Wout   = (const float*)d_in[11];
  const float* bout   = (const float*)d_in[12];
  float*       out    = (float*)d_out;

  const int S = in_sizes[0];          // 2048
  const int V = in_sizes[12];         // 50257
  const int T = out_size / V;         // 512

  // sentinel-fill the packed h slots (0x7F byte pattern)
  hipMemsetAsync(d_ws, 0x7F, 16384, stream);
  unsigned int*   hbuf = (unsigned int*)d_ws;
  unsigned short* Adec = (unsigned short*)((char*)d_ws + 65536);

  rnn_kernel<<<RNN_NWG, RNN_TPB, 0, stream>>>(state, emb, encWih, encWhh, encbih, encbhh,
                                              decWhh, decbih, decbhh, hbuf, Adec, S, T);
  int nvb = (V + 63) / 64;
  out_gemm<<<nvb, TPB, 0, stream>>>(Adec, Wout, bout, out, V);
  softmax_rows<<<T, TPB, 0, stream>>>(out, V);
}

// Round 5
// 11188.868 us; speedup vs baseline: 2.1225x; 2.1225x over previous
//
#include <hip/hip_runtime.h>
#include <stdint.h>
#include <math.h>

// Seq2seq LSTM, round-8 design.
// rnn_kernel: 64 WGs x 512 threads, __launch_bounds__(512, 2).
// THE FIX vs rounds 5/7: the second launch_bounds arg (2 waves/EU) raises the
// VGPR cap to 256, so the w[48] float4 weight file (192 VGPRs) is spill-free.
// (r5 capped at 128 -> spilled -> 20ms; r7 capped at 64 -> spilled -> 23ms.
// The low-fan-in sync design was never actually measured until now.)
//  - wave w owns units {2w, 2w+1} of the WG's 16 units (one 64B line/slot).
//  - poll: tid<256 read 16B each from the packed 4KB slot with ONE
//    global_load_dwordx4 sc0 sc1 (4K line-requests/round grid-wide,
//    32x less than r3's 131K).
//  - dot: 8 gate rows share each vec chunk; 17-shuffle merge-reduce leaves
//    lane l (l<8) holding the full sum of acc row l; lanes<8 write gate sums
//    to gshf[8w+l].
//  - cell+publish: wave 0 lanes 0..15 hold cs+bias for all 16 units, compute
//    the 16 cells, and issue ONE predicated 16-lane 64B line store (r5's
//    proven cheap publish; scattered dword publishes are banned per r4/r6).
//  - depth-1 xreg emb prefetch (tid 256..383) takes cold-HBM emb reads off
//    the critical path.
// Sentinel protocol byte-identical to verified rounds: 4-slot rotation,
// 0x7F7F7F7F, the SAME 16 threads clear slot (t+2)&3 post-gather and drain
// via vmcnt(0) before publishing h_{t+1}; the dot hides the drain.
//
// ws: [0]      hbuf: 4 slots x 1024 dwords = 16 KB (memset 0x7F)
//     [65536]  Adec: T x 1024 bf16 decoder hidden states (1 MB)

typedef __attribute__((ext_vector_type(8))) short short8;
typedef __attribute__((ext_vector_type(4))) float f32x4;
typedef __attribute__((ext_vector_type(4))) unsigned int u32x4;
typedef unsigned long long u64;
typedef unsigned int u32;

#define HD 1024
#define ED 512
#define TPB 256          // out_gemm / softmax block size
#define RNN_TPB 512
#define RNN_NWG 64
#define SENT32 0x7F7F7F7Fu

#define AGT __HIP_MEMORY_SCOPE_AGENT
#define RLX __ATOMIC_RELAXED

__device__ __forceinline__ unsigned short f2bf(float f) {
  union { float f; unsigned u; } x; x.f = f;
  unsigned u = x.u;
  u += 0x7fffu + ((u >> 16) & 1u);        // RNE
  return (unsigned short)(u >> 16);
}
__device__ __forceinline__ float frcp(float x) { return __builtin_amdgcn_rcpf(x); }
__device__ __forceinline__ float fsig(float x) { return frcp(1.0f + __expf(-x)); }
__device__ __forceinline__ float ftanh(float x) { return 1.0f - 2.0f * frcp(1.0f + __expf(2.0f * x)); }

#define DOT4(a, W, v) \
  a = fmaf((W).x, (v).x, fmaf((W).y, (v).y, fmaf((W).z, (v).z, fmaf((W).w, (v).w, (a)))))

// merge-reduce: r = full pairwise partial; lane&m selects which input survives
#define MRG2(r, a, b, m) { float _sa = __shfl_xor((a), (m)), _sb = __shfl_xor((b), (m)); \
                           (r) = (lane & (m)) ? ((b) + _sb) : ((a) + _sa); }

__global__ __launch_bounds__(RNN_TPB, 2)
void rnn_kernel(const int* __restrict__ state,
                const float* __restrict__ emb,
                const float* __restrict__ encWih,
                const float* __restrict__ encWhh,
                const float* __restrict__ encbih,
                const float* __restrict__ encbhh,
                const float* __restrict__ decWhh,
                const float* __restrict__ decbih,
                const float* __restrict__ decbhh,
                u32* __restrict__ hbuf,            // [4][1024] dwords (float payload)
                unsigned short* __restrict__ Adec, // [T][1024] bf16
                int S, int T) {
  __shared__ __align__(16) float vec[HD + ED];     // [h(1024) | x(512)]
  __shared__ __align__(16) float gshf[64];         // [unit(16)][gate(4)] sums

  const int tid  = threadIdx.x;
  const int wg   = blockIdx.x;
  const int w    = tid >> 6;           // wave 0..7: owns units {2w, 2w+1}
  const int lane = tid & 63;
  const int uA   = (wg << 4) + (w << 1);

  // ---- weights in registers: 48 x float4 = 192 VGPRs (fits under the
  // 256-VGPR cap granted by __launch_bounds__(512, 2)) ----
  // wr[g*4+j]      : unit A Whh row g, h-chunk j   (j=0..3)
  // wr[16+g*4+j]   : unit B Whh row g, h-chunk j
  // wr[32+g*2+j]   : unit A Wih row g, x-chunk j   (j=0..1)
  // wr[40+g*2+j]   : unit B Wih row g, x-chunk j
  float4 wr[48];
#pragma unroll
  for (int g = 0; g < 4; ++g) {
#pragma unroll
    for (int j = 0; j < 4; ++j) {
      wr[g * 4 + j]      = *(const float4*)&encWhh[((size_t)(g * HD) + uA) * HD + 4 * (lane + 64 * j)];
      wr[16 + g * 4 + j] = *(const float4*)&encWhh[((size_t)(g * HD) + uA + 1) * HD + 4 * (lane + 64 * j)];
    }
#pragma unroll
    for (int j = 0; j < 2; ++j) {
      wr[32 + g * 2 + j] = *(const float4*)&encWih[((size_t)(g * HD) + uA) * ED + 4 * (lane + 64 * j)];
      wr[40 + g * 2 + j] = *(const float4*)&encWih[((size_t)(g * HD) + uA + 1) * ED + 4 * (lane + 64 * j)];
    }
  }

  // ---- cell state + bias live in wave 0 lanes 0..15 (lane = local unit) ----
  float4 bias = {0.f, 0.f, 0.f, 0.f};
  float cs = 0.0f;
  if (tid < 16) {
    int u = (wg << 4) + tid;
    bias.x = encbih[u]          + encbhh[u];
    bias.y = encbih[HD + u]     + encbhh[HD + u];
    bias.z = encbih[2 * HD + u] + encbhh[2 * HD + u];
    bias.w = encbih[3 * HD + u] + encbhh[3 * HD + u];
  }

  // depth-1 emb prefetch (threads 256..383 stage x)
  float4 xreg = {0.f, 0.f, 0.f, 0.f};
  if (tid >= 256 && tid < 384) {
    int tok = state[0];
    xreg = *(const float4*)&emb[(size_t)tok * ED + 4 * (tid - 256)];
  }

  for (int t = 0; t < S + T; ++t) {
    const bool dec = (t >= S);
    if (t == S) {                      // one-time decoder weight switch
#pragma unroll
      for (int g = 0; g < 4; ++g)
#pragma unroll
        for (int j = 0; j < 4; ++j) {
          wr[g * 4 + j]      = *(const float4*)&decWhh[((size_t)(g * HD) + uA) * HD + 4 * (lane + 64 * j)];
          wr[16 + g * 4 + j] = *(const float4*)&decWhh[((size_t)(g * HD) + uA + 1) * HD + 4 * (lane + 64 * j)];
        }
      if (tid < 16) {
        int u = (wg << 4) + tid;
        bias.x = decbih[u]          + decbhh[u];
        bias.y = decbih[HD + u]     + decbhh[HD + u];
        bias.z = decbih[2 * HD + u] + decbhh[2 * HD + u];
        bias.w = decbih[3 * HD + u] + decbhh[3 * HD + u];
      }
    }

    // ---- gather: tid<256 poll 16B each (ONE dwordx4); 256..383 stage x ----
    if (tid < 256) {
      if (t == 0) {
        *(float4*)&vec[4 * tid] = make_float4(0.f, 0.f, 0.f, 0.f);
      } else {
        const u32* L = hbuf + (((size_t)(t & 3)) << 10) + (tid << 2);
        u32x4 d;
        do {
          asm volatile("global_load_dwordx4 %0, %1, off sc0 sc1\n\t"
                       "s_waitcnt vmcnt(0)"
                       : "=v"(d) : "v"(L) : "memory");
        } while (d.x == SENT32 || d.y == SENT32 || d.z == SENT32 || d.w == SENT32);
        union { u32x4 u; float4 f; } p; p.u = d;
        *(float4*)&vec[4 * tid] = p.f;
      }
    } else if (tid < 384) {
      if (!dec) {
        *(float4*)&vec[HD + 4 * (tid - 256)] = xreg;   // x_t (prefetched)
        if (t + 1 < S) {
          int tok = state[t + 1];
          xreg = *(const float4*)&emb[(size_t)tok * ED + 4 * (tid - 256)];
        }
      }
    }
    __syncthreads();

    // ---- re-sentinel own line in slot (t+2)&3: same 16 threads that will
    // publish there at step t+1; drained by their vmcnt(0) below. Safe by the
    // transitive-gather proof (slot held h_{t-2}, all WGs are past it). ----
    if (tid < 16)
      __hip_atomic_store(&hbuf[(((size_t)((t + 2) & 3)) << 10) + (wg << 4) + tid], SENT32, RLX, AGT);

    // ---- dot: 8 gate rows (2 units x 4 gates) share each vec chunk ----
    float a0 = 0.f, a1 = 0.f, a2 = 0.f, a3 = 0.f;
    float a4 = 0.f, a5 = 0.f, a6 = 0.f, a7 = 0.f;
#pragma unroll
    for (int j = 0; j < 4; ++j) {
      float4 v = *(const float4*)&vec[4 * (lane + 64 * j)];
      DOT4(a0, wr[0 * 4 + j], v);  DOT4(a1, wr[1 * 4 + j], v);
      DOT4(a2, wr[2 * 4 + j], v);  DOT4(a3, wr[3 * 4 + j], v);
      DOT4(a4, wr[16 + 0 * 4 + j], v);  DOT4(a5, wr[16 + 1 * 4 + j], v);
      DOT4(a6, wr[16 + 2 * 4 + j], v);  DOT4(a7, wr[16 + 3 * 4 + j], v);
    }
    if (!dec) {
#pragma unroll
      for (int j = 0; j < 2; ++j) {
        float4 v = *(const float4*)&vec[HD + 4 * (lane + 64 * j)];
        DOT4(a0, wr[32 + 0 * 2 + j], v);  DOT4(a1, wr[32 + 1 * 2 + j], v);
        DOT4(a2, wr[32 + 2 * 2 + j], v);  DOT4(a3, wr[32 + 3 * 2 + j], v);
        DOT4(a4, wr[40 + 0 * 2 + j], v);  DOT4(a5, wr[40 + 1 * 2 + j], v);
        DOT4(a6, wr[40 + 2 * 2 + j], v);  DOT4(a7, wr[40 + 3 * 2 + j], v);
      }
    }
    // ---- merge-reduce (17 shuffles): lane l<8 ends with full sum of row l
    // (row = gate + 4*unitLocal within this wave) ----
    float m0, m1, m2, m3, n0, n1, vv;
    MRG2(m0, a0, a1, 1);  MRG2(m1, a2, a3, 1);
    MRG2(m2, a4, a5, 1);  MRG2(m3, a6, a7, 1);
    MRG2(n0, m0, m1, 2);  MRG2(n1, m2, m3, 2);
    MRG2(vv, n0, n1, 4);
    vv += __shfl_xor(vv, 8);
    vv += __shfl_xor(vv, 16);
    vv += __shfl_xor(vv, 32);
    if (lane < 8) gshf[8 * w + lane] = vv;   // == gshf[unit*4 + gate]
    __syncthreads();                         // also protects vec for next step

    // ---- cell + publish: wave 0 lanes 0..15, ONE 64B line store ----
    if (tid < 16) {
      float4 gs = *(const float4*)&gshf[4 * tid];
      float iv = fsig(gs.x + bias.x);
      float fv = fsig(gs.y + bias.y);
      float gv = ftanh(gs.z + bias.z);
      float ov = fsig(gs.w + bias.w);
      cs = fv * cs + iv * gv;
      float hv = ov * ftanh(cs);
      // drain these threads' sentinel-clear of the target slot (issued at
      // step t-1); the dot above already hid its latency
      asm volatile("s_waitcnt vmcnt(0)" ::: "memory");
      union { float f; u32 u; } x; x.f = hv;
      __hip_atomic_store(&hbuf[(((size_t)((t + 1) & 3)) << 10) + (wg << 4) + tid], x.u, RLX, AGT);
      if (dec) Adec[(size_t)(t - S) * HD + (wg << 4) + tid] = f2bf(hv);
    }
  }
}

// ---- output head GEMM: out[t][v] = Adec[t] . Wout[v] + bout[v] ----
// WG tile: 512 t x 64 v. Wave w: t in [w*128, w*128+128), v in [v0, v0+64).
// Per k-step (K=32): stage A-slice (512x32 bf16, padded stride) in LDS,
// 8 a-frags + 4 b-frags -> 32 MFMA per wave. Wout (206 MB) read exactly once.
#define AST 56   // Alds row stride in ushorts

__global__ __launch_bounds__(TPB)
void out_gemm(const unsigned short* __restrict__ Adec,
              const float* __restrict__ Wout,
              const float* __restrict__ bout,
              float* __restrict__ out,
              int V) {
  __shared__ __align__(16) unsigned short Alds[512 * AST]; // 56 KB
  const int tid  = threadIdx.x;
  const int wv   = tid >> 6;
  const int lane = tid & 63;
  const int col  = lane & 15;
  const int quad = lane >> 4;
  const int v0   = blockIdx.x * 64;

  f32x4 acc[4][8];
#pragma unroll
  for (int bt = 0; bt < 4; ++bt)
#pragma unroll
    for (int tt = 0; tt < 8; ++tt)
      acc[bt][tt] = (f32x4){0.f, 0.f, 0.f, 0.f};

  for (int k0 = 0; k0 < HD; k0 += 32) {
    __syncthreads();
    // stage A k-slice: 512 rows x 32 bf16 (4 x uint4 chunks per row)
#pragma unroll
    for (int i = 0; i < 8; ++i) {
      int id = tid + (i << 8);             // 0..2047
      int rt = id >> 2, c4 = id & 3;
      uint4 d = *(const uint4*)(Adec + rt * HD + k0 + (c4 << 3));
      *(uint4*)&Alds[rt * AST + (c4 << 3)] = d;
    }
    __syncthreads();
    // B fragments from global (fp32 -> bf16): lane l covers Wout[v0+bt*16+col][k0+quad*8 ..+7]
    short8 bf[4];
#pragma unroll
    for (int bt = 0; bt < 4; ++bt) {
      int v = v0 + (bt << 4) + col;
      if (v >= V) v = V - 1;
      const float4* wp = (const float4*)(Wout + (size_t)v * HD + k0 + (quad << 3));
      float4 w0 = wp[0], w1 = wp[1];
      short8 b;
      b[0] = (short)f2bf(w0.x); b[1] = (short)f2bf(w0.y);
      b[2] = (short)f2bf(w0.z); b[3] = (short)f2bf(w0.w);
      b[4] = (short)f2bf(w1.x); b[5] = (short)f2bf(w1.y);
      b[6] = (short)f2bf(w1.z); b[7] = (short)f2bf(w1.w);
      bf[bt] = b;
    }
#pragma unroll
    for (int tt = 0; tt < 8; ++tt) {
      int trow = (wv << 7) + (tt << 4) + col;
      short8 af = *(const short8*)&Alds[trow * AST + (quad << 3)];
#pragma unroll
      for (int bt = 0; bt < 4; ++bt)
        acc[bt][tt] = __builtin_amdgcn_mfma_f32_16x16x32_bf16(af, bf[bt], acc[bt][tt], 0, 0, 0);
    }
  }
  // epilogue: C/D layout col = lane&15 (v), row = quad*4 + reg (t)
#pragma unroll
  for (int bt = 0; bt < 4; ++bt) {
    int v = v0 + (bt << 4) + col;
    if (v < V) {
      float bb = bout[v];
#pragma unroll
      for (int tt = 0; tt < 8; ++tt) {
        int tb = (wv << 7) + (tt << 4) + (quad << 2);
        f32x4 a = acc[bt][tt];
        out[(size_t)(tb + 0) * V + v] = a[0] + bb;
        out[(size_t)(tb + 1) * V + v] = a[1] + bb;
        out[(size_t)(tb + 2) * V + v] = a[2] + bb;
        out[(size_t)(tb + 3) * V + v] = a[3] + bb;
      }
    }
  }
}

// ---- row softmax in place over d_out: one WG per t ----
__global__ __launch_bounds__(TPB)
void softmax_rows(float* __restrict__ out, int V) {
  float* rowp = out + (size_t)blockIdx.x * V;
  __shared__ float red[8];
  const int tid = threadIdx.x;

  float m = -1e30f;
  for (int v = tid; v < V; v += TPB) m = fmaxf(m, rowp[v]);
#pragma unroll
  for (int off = 32; off >= 1; off >>= 1) m = fmaxf(m, __shfl_xor(m, off));
  if ((tid & 63) == 0) red[tid >> 6] = m;
  __syncthreads();
  if (tid == 0) red[4] = fmaxf(fmaxf(red[0], red[1]), fmaxf(red[2], red[3]));
  __syncthreads();
  m = red[4];

  float s = 0.0f;
  for (int v = tid; v < V; v += TPB) {
    float e = expf(rowp[v] - m);
    rowp[v] = e;
    s += e;
  }
#pragma unroll
  for (int off = 32; off >= 1; off >>= 1) s += __shfl_xor(s, off);
  if ((tid & 63) == 0) red[tid >> 6] = s;
  __syncthreads();
  if (tid == 0) red[5] = red[0] + red[1] + red[2] + red[3];
  __syncthreads();
  float inv = 1.0f / red[5];
  for (int v = tid; v < V; v += TPB) rowp[v] *= inv;
}

extern "C" void kernel_launch(void* const* d_in, const int* in_sizes, int n_in,
                              void* d_out, int out_size, void* d_ws, size_t ws_size,
                              hipStream_t stream) {
  const int*   state  = (const int*)d_in[0];
  // d_in[1] = max_len scalar (T derived from out_size instead)
  const float* emb    = (const float*)d_in[2];
  const float* encWih = (const float*)d_in[3];
  const float* encWhh = (const float*)d_in[4];
  const float* encbih = (const float*)d_in[5];
  const float* encbhh = (const float*)d_in[6];
  // d_in[7] = dec_Wih (multiplied by zero input in reference -> unused)
  const float* decWhh = (const float*)d_in[8];
  const float* decbih = (const float*)d_in[9];
  const float* decbhh = (const float*)d_in[10];
  const float* Wout   = (const float*)d_in[11];
  const float* bout   = (const float*)d_in[12];
  float*       out    = (float*)d_out;

  const int S = in_sizes[0];          // 2048
  const int V = in_sizes[12];         // 50257
  const int T = out_size / V;         // 512

  // sentinel-fill the packed h slots (0x7F byte pattern)
  hipMemsetAsync(d_ws, 0x7F, 16384, stream);
  u32*            hbuf = (u32*)d_ws;
  unsigned short* Adec = (unsigned short*)((char*)d_ws + 65536);

  rnn_kernel<<<RNN_NWG, RNN_TPB, 0, stream>>>(state, emb, encWih, encWhh, encbih, encbhh,
                                              decWhh, decbih, decbhh, hbuf, Adec, S, T);
  int nvb = (V + 63) / 64;
  out_gemm<<<nvb, TPB, 0, stream>>>(Adec, Wout, bout, out, V);
  softmax_rows<<<T, TPB, 0, stream>>>(out, V);
}